// Round 4
// baseline (166.398 us; speedup 1.0000x reference)
//
#include <hip/hip_runtime.h>

constexpr int CODE_LEN = 1024;
constexpr int INFO_LEN = 512;
constexpr int BATCH    = 2048;
constexpr int ITERS    = 5;
#define CLIPV 15.0f

// f(a,b): v_min(|a|,|b|) + v_xor(sign) + v_or = 3 VALU
__device__ __forceinline__ float fop(float a, float b) {
    float m = fminf(fabsf(a), fabsf(b));
    unsigned s = (__float_as_uint(a) ^ __float_as_uint(b)) & 0x80000000u;
    return __uint_as_float(__float_as_uint(m) | s);
}
// clip = single v_med3_f32
__device__ __forceinline__ float clipf(float x) {
    return __builtin_amdgcn_fmed3f(x, -CLIPV, CLIPV);
}

// One wave per codeword; lane owns words [16*lane, 16*lane+15].
// stg[s] = left[s+1] before the right pass, right[s+1] after it; the left
// pass rewrites stg[s-1] = left[s]. stg[9] = rx, read-only (right[10] is
// never consumed). Stages 0-3 are in-lane; 4-9 are __shfl_xor (masks 1..32).
// No __syncthreads in the hot loop. launch_bounds(256,1): empirically the
// compiler caps VGPRs at ~256/w for second arg w, so w=1 -> 256-reg budget
// (R2/R3 spilled at w=2/4 -> 128/64 regs).
__global__ __launch_bounds__(256, 1) void polar_bp_r4(const float* __restrict__ rx,
                                                      const int* __restrict__ info,
                                                      float* __restrict__ out) {
    __shared__ int RK[CODE_LEN];          // init-only: word -> output rank / -1
    const int t = threadIdx.x;
#pragma unroll
    for (int k = 0; k < 4; ++k) RK[t + 256 * k] = -1;
    __syncthreads();
#pragma unroll
    for (int k = 0; k < 2; ++k) { int kk = t + 256 * k; RK[info[kk]] = kk; }
    __syncthreads();

    const int lane = t & 63;
    const int b    = blockIdx.x * 4 + (t >> 6);

    int   rk[16];
    float fr[16];
#pragma unroll
    for (int j = 0; j < 16; ++j) {
        rk[j] = RK[16 * lane + j];
        fr[j] = (rk[j] < 0) ? CLIPV : 0.f;   // right[0] frozen vector
    }

    float stg[10][16];
    const float4* rxv = (const float4*)(rx + (size_t)b * CODE_LEN + 16 * lane);
#pragma unroll
    for (int q = 0; q < 4; ++q) {
        float4 v = rxv[q];
        stg[9][4 * q + 0] = v.x; stg[9][4 * q + 1] = v.y;
        stg[9][4 * q + 2] = v.z; stg[9][4 * q + 3] = v.w;
    }
#pragma unroll
    for (int s = 0; s < 9; ++s)
#pragma unroll
        for (int j = 0; j < 16; ++j) stg[s][j] = 0.f;

#pragma unroll 1
    for (int it = 0; it < ITERS; ++it) {
        // ========================= RIGHT pass (s = 0..8) =========================
        // s = 0: r = frozen vector
#pragma unroll
        for (int j = 0; j < 16; j += 2) {
            float l0 = stg[0][j], l1 = stg[0][j + 1];
            float nu = clipf(fop(fr[j], l1 + fr[j + 1]));
            float nl = clipf(fop(fr[j], l0) + fr[j + 1]);
            stg[0][j] = nu; stg[0][j + 1] = nl;
        }
        // s = 1..3: in-lane butterflies
#pragma unroll
        for (int s = 1; s <= 3; ++s) {
            const int st = 1 << s;
#pragma unroll
            for (int j = 0; j < 16; ++j) if (!(j & st)) {
                const int p = j + st;
                float ru = stg[s - 1][j], rl = stg[s - 1][p];
                float lu = stg[s][j],     ll = stg[s][p];
                stg[s][j] = clipf(fop(ru, ll + rl));
                stg[s][p] = clipf(fop(ru, lu) + rl);
            }
        }
        // s = 4..8: cross-lane; exchange exactly what the partner needs
#pragma unroll
        for (int s = 4; s <= 8; ++s) {
            const int  lm = 1 << (s - 4);
            const bool up = (lane & lm) == 0;
#pragma unroll
            for (int j = 0; j < 16; ++j) {
                float r = stg[s - 1][j], l = stg[s][j];
                float snd = up ? fop(r, l) : (l + r);
                float rc  = __shfl_xor(snd, lm, 64);
                stg[s][j] = clipf(up ? fop(r, rc) : (rc + r));
            }
        }
        // ========================= LEFT pass (s = 9..0) ==========================
        // s = 9..4: cross-lane (stg[9] = rx stays read-only)
#pragma unroll
        for (int s = 9; s >= 4; --s) {
            const int  lm = 1 << (s - 4);
            const bool up = (lane & lm) == 0;
#pragma unroll
            for (int j = 0; j < 16; ++j) {
                float r = stg[s - 1][j], l = stg[s][j];
                float snd = up ? fop(r, l) : (l + r);
                float rc  = __shfl_xor(snd, lm, 64);
                stg[s - 1][j] = clipf(up ? fop(l, rc) : (rc + l));
            }
        }
        // s = 3..1: in-lane butterflies
#pragma unroll
        for (int s = 3; s >= 1; --s) {
            const int st = 1 << s;
#pragma unroll
            for (int j = 0; j < 16; ++j) if (!(j & st)) {
                const int p = j + st;
                float lu = stg[s][j],     ll = stg[s][p];
                float ru = stg[s - 1][j], rl = stg[s - 1][p];
                stg[s - 1][j] = clipf(fop(lu, ll + rl));
                stg[s - 1][p] = clipf(fop(ru, lu) + ll);
            }
        }
        // s = 0: emit left[0] at info positions (right[0] = 0 there)
        float* ob  = out + ((size_t)it * BATCH + b) * INFO_LEN;
        float* ob2 = out + ((size_t)ITERS * BATCH + b) * INFO_LEN;
        const bool last = (it == ITERS - 1);
#pragma unroll
        for (int j = 0; j < 16; j += 2) {
            float l0 = stg[0][j], l1 = stg[0][j + 1];
            float v0 = clipf(fop(l0, l1 + fr[j + 1]));
            float v1 = clipf(fop(fr[j], l0) + l1);
            if (rk[j]     >= 0) { ob[rk[j]] = v0;     if (last) ob2[rk[j]] = v0; }
            if (rk[j + 1] >= 0) { ob[rk[j + 1]] = v1; if (last) ob2[rk[j + 1]] = v1; }
        }
    }
}

extern "C" void kernel_launch(void* const* d_in, const int* in_sizes, int n_in,
                              void* d_out, int out_size, void* d_ws, size_t ws_size,
                              hipStream_t stream) {
    const float* rx   = (const float*)d_in[0];
    const int*   info = (const int*)d_in[1];
    float*       outp = (float*)d_out;
    polar_bp_r4<<<dim3(BATCH / 4), dim3(256), 0, stream>>>(rx, info, outp);
}

// Round 5
// 99.092 us; speedup vs baseline: 1.6792x; 1.6792x over previous
//
#include <hip/hip_runtime.h>

constexpr int CODE_LEN = 1024;
constexpr int INFO_LEN = 512;
constexpr int BATCH    = 2048;
constexpr int ITERS    = 5;
#define CLIPV 15.0f

// f(a,b): v_min(|a|,|b|) + v_xor(sign) + v_and_or = 3 VALU
__device__ __forceinline__ float fop(float a, float b) {
    float m = fminf(fabsf(a), fabsf(b));
    unsigned s = (__float_as_uint(a) ^ __float_as_uint(b)) & 0x80000000u;
    return __uint_as_float(__float_as_uint(m) | s);
}
// clip = single v_med3_f32
__device__ __forceinline__ float clipf(float x) {
    return __builtin_amdgcn_fmed3f(x, -CLIPV, CLIPV);
}

// 2 waves per codeword, 8 words/lane (word = w*512 + lane*8 + j).
// stg[s] = left[s+1] before the right pass, right[s+1] after; left pass
// rewrites stg[s-1] = left[s]. stg[9] = rx (read-only). Stages 0-2 in-lane,
// 3-8 = __shfl_xor (masks 1..32), 9 = one LDS exchange (1 barrier/iter,
// double-buffered). Register budget: launch_bounds(256,2) -> 128-VGPR cap
// (empirical: cap ~= 256/w; R2 w=2->128, R3 w=4->64, R4 w=1->172 used).
// State: stg 80 + fr 8 + temps ~20 ~= 110 < 128 -> no spill, 4 waves/SIMD.
__global__ __launch_bounds__(256, 2) void polar_bp_r5(const float* __restrict__ rx,
                                                      const int* __restrict__ info,
                                                      float* __restrict__ out) {
    __shared__ int   RK[CODE_LEN];   // word -> output rank or -1 (read at emit)
    __shared__ float X[2][8][256];   // cross-wave exchange, double-buffered
    const int t = threadIdx.x;
#pragma unroll
    for (int k = 0; k < 4; ++k) RK[t + 256 * k] = -1;
    __syncthreads();
#pragma unroll
    for (int k = 0; k < 2; ++k) { int kk = t + 256 * k; RK[info[kk]] = kk; }
    __syncthreads();

    const int lane = t & 63;
    const int w    = (t >> 6) & 1;            // wave within the codeword pair
    const int b    = blockIdx.x * 2 + (t >> 7);
    const int base = w * 512 + lane * 8;      // codeword-local word base

    float fr[8];
#pragma unroll
    for (int j = 0; j < 8; ++j)
        fr[j] = (RK[base + j] < 0) ? CLIPV : 0.f;   // right[0] frozen vector

    float stg[10][8];
    const float4* rxv = (const float4*)(rx + (size_t)b * CODE_LEN + base);
#pragma unroll
    for (int q = 0; q < 2; ++q) {
        float4 v = rxv[q];
        stg[9][4 * q + 0] = v.x; stg[9][4 * q + 1] = v.y;
        stg[9][4 * q + 2] = v.z; stg[9][4 * q + 3] = v.w;
    }
#pragma unroll
    for (int s = 0; s < 9; ++s)
#pragma unroll
        for (int j = 0; j < 8; ++j) stg[s][j] = 0.f;

#pragma unroll 1
    for (int it = 0; it < ITERS; ++it) {
        // ---------------- RIGHT pass ----------------
        // s = 0: r = frozen vector
#pragma unroll
        for (int j = 0; j < 8; j += 2) {
            float l0 = stg[0][j], l1 = stg[0][j + 1];
            float nu = clipf(fop(fr[j], l1 + fr[j + 1]));
            float nl = clipf(fop(fr[j], l0) + fr[j + 1]);
            stg[0][j] = nu; stg[0][j + 1] = nl;
        }
        // s = 1,2: in-lane butterflies
#pragma unroll
        for (int s = 1; s <= 2; ++s) {
            const int st = 1 << s;
#pragma unroll
            for (int j = 0; j < 8; ++j) if (!(j & st)) {
                const int p = j + st;
                float ru = stg[s - 1][j], rl = stg[s - 1][p];
                float lu = stg[s][j],     ll = stg[s][p];
                stg[s][j] = clipf(fop(ru, ll + rl));
                stg[s][p] = clipf(fop(ru, lu) + rl);
            }
        }
        // s = 3..8: cross-lane; send exactly what the partner needs
#pragma unroll
        for (int s = 3; s <= 8; ++s) {
            const int  lm = 1 << (s - 3);
            const bool up = (lane & lm) == 0;
#pragma unroll
            for (int j = 0; j < 8; ++j) {
                float r = stg[s - 1][j], l = stg[s][j];
                float snd = up ? fop(r, l) : (l + r);
                float rc  = __shfl_xor(snd, lm, 64);
                stg[s][j] = clipf(up ? fop(r, rc) : (rc + r));
            }
        }
        // ---------------- LEFT pass -----------------
        // s = 9: cross-wave exchange via LDS (stg[9]=rx read-only, r=stg[8])
        {
            float (*buf)[256] = X[it & 1];
#pragma unroll
            for (int j = 0; j < 8; ++j) {
                float r = stg[8][j], l = stg[9][j];
                buf[j][t] = (w == 0) ? fop(r, l) : (l + r);
            }
            __syncthreads();
#pragma unroll
            for (int j = 0; j < 8; ++j) {
                float rc = buf[j][t ^ 64];
                float l  = stg[9][j];
                stg[8][j] = clipf((w == 0) ? fop(l, rc) : (rc + l));
            }
        }
        // s = 8..3: cross-lane
#pragma unroll
        for (int s = 8; s >= 3; --s) {
            const int  lm = 1 << (s - 3);
            const bool up = (lane & lm) == 0;
#pragma unroll
            for (int j = 0; j < 8; ++j) {
                float r = stg[s - 1][j], l = stg[s][j];
                float snd = up ? fop(r, l) : (l + r);
                float rc  = __shfl_xor(snd, lm, 64);
                stg[s - 1][j] = clipf(up ? fop(l, rc) : (rc + l));
            }
        }
        // s = 2,1: in-lane butterflies
#pragma unroll
        for (int s = 2; s >= 1; --s) {
            const int st = 1 << s;
#pragma unroll
            for (int j = 0; j < 8; ++j) if (!(j & st)) {
                const int p = j + st;
                float lu = stg[s][j],     ll = stg[s][p];
                float ru = stg[s - 1][j], rl = stg[s - 1][p];
                stg[s - 1][j] = clipf(fop(lu, ll + rl));
                stg[s - 1][p] = clipf(fop(ru, lu) + ll);
            }
        }
        // s = 0: emit left[0] at info positions (right[0] = 0 there);
        // ranks come from LDS (saves 8 VGPRs vs register rk[])
        float* ob  = out + ((size_t)it * BATCH + b) * INFO_LEN;
        float* ob2 = out + ((size_t)ITERS * BATCH + b) * INFO_LEN;
        const bool last = (it == ITERS - 1);
#pragma unroll
        for (int j = 0; j < 8; j += 2) {
            float l0 = stg[0][j], l1 = stg[0][j + 1];
            float v0 = clipf(fop(l0, l1 + fr[j + 1]));
            float v1 = clipf(fop(fr[j], l0) + l1);
            int r0 = RK[base + j], r1 = RK[base + j + 1];
            if (r0 >= 0) { ob[r0] = v0; if (last) ob2[r0] = v0; }
            if (r1 >= 0) { ob[r1] = v1; if (last) ob2[r1] = v1; }
        }
    }
}

extern "C" void kernel_launch(void* const* d_in, const int* in_sizes, int n_in,
                              void* d_out, int out_size, void* d_ws, size_t ws_size,
                              hipStream_t stream) {
    const float* rx   = (const float*)d_in[0];
    const int*   info = (const int*)d_in[1];
    float*       outp = (float*)d_out;
    polar_bp_r5<<<dim3(BATCH / 2), dim3(256), 0, stream>>>(rx, info, outp);
}

// Round 6
// 70.345 us; speedup vs baseline: 2.3655x; 1.4087x over previous
//
#include <hip/hip_runtime.h>

constexpr int CODE_LEN = 1024;
constexpr int INFO_LEN = 512;
constexpr int BATCH    = 2048;
constexpr int ITERS    = 5;
#define CLIPV 15.0f

// f(a,b): v_min(|a|,|b|) + v_xor(sign) + v_and_or = 3 VALU
__device__ __forceinline__ float fop(float a, float b) {
    float m = fminf(fabsf(a), fabsf(b));
    unsigned s = (__float_as_uint(a) ^ __float_as_uint(b)) & 0x80000000u;
    return __uint_as_float(__float_as_uint(m) | s);
}
// clip = single v_med3_f32
__device__ __forceinline__ float clipf(float x) {
    return __builtin_amdgcn_fmed3f(x, -CLIPV, CLIPV);
}

// 4 waves per codeword, 4 words/lane (thread t owns words 4t..4t+3 of its
// codeword). stg[s] = left[s+1] before the right pass, right[s+1] after it;
// the left pass rewrites stg[s-1] = left[s]; stg[9] = rx (read-only).
// Stages 0,1 in-lane; 2..7 = __shfl_xor masks 1..32; 8,9 cross-wave via two
// alternating LDS buffers, ONE barrier per exchange (strict alternation makes
// each buffer's reuse barrier-separated: use k reads before bar(k+1), use k+2
// writes after it). 3 barriers/iter.
// Register budget: launch_bounds(256,4) -> 64-VGPR cap (empirical cap~256/w).
// State = stg 40 + fr 4 + temps ~14 < 64 -> no spill, 8 waves/SIMD possible;
// grid 2048 blocks = 8 blocks/CU = 32 waves/CU.
__global__ __launch_bounds__(256, 4) void polar_bp_r6(const float* __restrict__ rx,
                                                      const int* __restrict__ info,
                                                      float* __restrict__ out) {
    __shared__ int   RK[CODE_LEN];    // word -> output rank or -1
    __shared__ float X[2][CODE_LEN];  // cross-wave exchange, alternating
    const int t = threadIdx.x;
    const int b = blockIdx.x;

#pragma unroll
    for (int k = 0; k < 4; ++k) RK[t + 256 * k] = -1;
    __syncthreads();
#pragma unroll
    for (int k = 0; k < 2; ++k) { int kk = t + 256 * k; RK[info[kk]] = kk; }
    __syncthreads();

    float fr[4];
    {
        int4 rkv = *(const int4*)&RK[4 * t];
        fr[0] = (rkv.x < 0) ? CLIPV : 0.f;
        fr[1] = (rkv.y < 0) ? CLIPV : 0.f;
        fr[2] = (rkv.z < 0) ? CLIPV : 0.f;
        fr[3] = (rkv.w < 0) ? CLIPV : 0.f;
    }

    float stg[10][4];
    {
        float4 v = *(const float4*)(rx + (size_t)b * CODE_LEN + 4 * t);
        stg[9][0] = v.x; stg[9][1] = v.y; stg[9][2] = v.z; stg[9][3] = v.w;
    }
#pragma unroll
    for (int s = 0; s < 9; ++s)
#pragma unroll
        for (int j = 0; j < 4; ++j) stg[s][j] = 0.f;

#pragma unroll 1
    for (int it = 0; it < ITERS; ++it) {
        float* bufA = X[it & 1];        // right-s8 and left-s8
        float* bufB = X[(it & 1) ^ 1];  // left-s9
        // ---------------- RIGHT pass ----------------
        // s = 0: r = frozen; pairs (0,1),(2,3)
        {
            float l0 = stg[0][0], l1 = stg[0][1], l2 = stg[0][2], l3 = stg[0][3];
            stg[0][0] = clipf(fop(fr[0], l1 + fr[1]));
            stg[0][1] = clipf(fop(fr[0], l0) + fr[1]);
            stg[0][2] = clipf(fop(fr[2], l3 + fr[3]));
            stg[0][3] = clipf(fop(fr[2], l2) + fr[3]);
        }
        // s = 1: pairs (0,2),(1,3), in-lane
        {
            float ru0 = stg[0][0], ru1 = stg[0][1], rl0 = stg[0][2], rl1 = stg[0][3];
            float lu0 = stg[1][0], lu1 = stg[1][1], ll0 = stg[1][2], ll1 = stg[1][3];
            stg[1][0] = clipf(fop(ru0, ll0 + rl0));
            stg[1][2] = clipf(fop(ru0, lu0) + rl0);
            stg[1][1] = clipf(fop(ru1, ll1 + rl1));
            stg[1][3] = clipf(fop(ru1, lu1) + rl1);
        }
        // s = 2..7: in-wave shuffles
#pragma unroll
        for (int s = 2; s <= 7; ++s) {
            const int  lm = 1 << (s - 2);
            const bool up = (t & lm) == 0;
#pragma unroll
            for (int j = 0; j < 4; ++j) {
                float r = stg[s - 1][j], l = stg[s][j];
                float snd = up ? fop(r, l) : (l + r);
                float rc  = __shfl_xor(snd, lm, 64);
                stg[s][j] = clipf(up ? fop(r, rc) : (rc + r));
            }
        }
        // s = 8: cross-wave (partner t^64) via bufA
        {
            const bool up = (t & 64) == 0;
            float4 sv;
            sv.x = up ? fop(stg[7][0], stg[8][0]) : (stg[8][0] + stg[7][0]);
            sv.y = up ? fop(stg[7][1], stg[8][1]) : (stg[8][1] + stg[7][1]);
            sv.z = up ? fop(stg[7][2], stg[8][2]) : (stg[8][2] + stg[7][2]);
            sv.w = up ? fop(stg[7][3], stg[8][3]) : (stg[8][3] + stg[7][3]);
            *(float4*)&bufA[4 * t] = sv;
            __syncthreads();
            float4 rv = *(const float4*)&bufA[4 * (t ^ 64)];
            stg[8][0] = clipf(up ? fop(stg[7][0], rv.x) : (rv.x + stg[7][0]));
            stg[8][1] = clipf(up ? fop(stg[7][1], rv.y) : (rv.y + stg[7][1]));
            stg[8][2] = clipf(up ? fop(stg[7][2], rv.z) : (rv.z + stg[7][2]));
            stg[8][3] = clipf(up ? fop(stg[7][3], rv.w) : (rv.w + stg[7][3]));
        }
        // ---------------- LEFT pass -----------------
        // s = 9: cross-wave (partner t^128) via bufB; l = stg[9]=rx, r = stg[8]
        {
            const bool up = (t & 128) == 0;
            float4 sv;
            sv.x = up ? fop(stg[8][0], stg[9][0]) : (stg[9][0] + stg[8][0]);
            sv.y = up ? fop(stg[8][1], stg[9][1]) : (stg[9][1] + stg[8][1]);
            sv.z = up ? fop(stg[8][2], stg[9][2]) : (stg[9][2] + stg[8][2]);
            sv.w = up ? fop(stg[8][3], stg[9][3]) : (stg[9][3] + stg[8][3]);
            *(float4*)&bufB[4 * t] = sv;
            __syncthreads();
            float4 rv = *(const float4*)&bufB[4 * (t ^ 128)];
            stg[8][0] = clipf(up ? fop(stg[9][0], rv.x) : (rv.x + stg[9][0]));
            stg[8][1] = clipf(up ? fop(stg[9][1], rv.y) : (rv.y + stg[9][1]));
            stg[8][2] = clipf(up ? fop(stg[9][2], rv.z) : (rv.z + stg[9][2]));
            stg[8][3] = clipf(up ? fop(stg[9][3], rv.w) : (rv.w + stg[9][3]));
        }
        // s = 8: cross-wave (partner t^64) via bufA; l = stg[8], r = stg[7]
        {
            const bool up = (t & 64) == 0;
            float4 sv;
            sv.x = up ? fop(stg[7][0], stg[8][0]) : (stg[8][0] + stg[7][0]);
            sv.y = up ? fop(stg[7][1], stg[8][1]) : (stg[8][1] + stg[7][1]);
            sv.z = up ? fop(stg[7][2], stg[8][2]) : (stg[8][2] + stg[7][2]);
            sv.w = up ? fop(stg[7][3], stg[8][3]) : (stg[8][3] + stg[7][3]);
            *(float4*)&bufA[4 * t] = sv;
            __syncthreads();
            float4 rv = *(const float4*)&bufA[4 * (t ^ 64)];
            stg[7][0] = clipf(up ? fop(stg[8][0], rv.x) : (rv.x + stg[8][0]));
            stg[7][1] = clipf(up ? fop(stg[8][1], rv.y) : (rv.y + stg[8][1]));
            stg[7][2] = clipf(up ? fop(stg[8][2], rv.z) : (rv.z + stg[8][2]));
            stg[7][3] = clipf(up ? fop(stg[8][3], rv.w) : (rv.w + stg[8][3]));
        }
        // s = 7..2: in-wave shuffles
#pragma unroll
        for (int s = 7; s >= 2; --s) {
            const int  lm = 1 << (s - 2);
            const bool up = (t & lm) == 0;
#pragma unroll
            for (int j = 0; j < 4; ++j) {
                float r = stg[s - 1][j], l = stg[s][j];
                float snd = up ? fop(r, l) : (l + r);
                float rc  = __shfl_xor(snd, lm, 64);
                stg[s - 1][j] = clipf(up ? fop(l, rc) : (rc + l));
            }
        }
        // s = 1: in-lane, pairs (0,2),(1,3); l = stg[1], r = stg[0] -> stg[0]
        {
            float lu0 = stg[1][0], lu1 = stg[1][1], ll0 = stg[1][2], ll1 = stg[1][3];
            float ru0 = stg[0][0], ru1 = stg[0][1], rl0 = stg[0][2], rl1 = stg[0][3];
            stg[0][0] = clipf(fop(lu0, ll0 + rl0));
            stg[0][2] = clipf(fop(ru0, lu0) + ll0);
            stg[0][1] = clipf(fop(lu1, ll1 + rl1));
            stg[0][3] = clipf(fop(ru1, lu1) + ll1);
        }
        // s = 0: emit left[0] at info positions (right[0] = 0 there)
        {
            float v0 = clipf(fop(stg[0][0], stg[0][1] + fr[1]));
            float v1 = clipf(fop(fr[0], stg[0][0]) + stg[0][1]);
            float v2 = clipf(fop(stg[0][2], stg[0][3] + fr[3]));
            float v3 = clipf(fop(fr[2], stg[0][2]) + stg[0][3]);
            int4 rkv = *(const int4*)&RK[4 * t];
            float* ob  = out + ((size_t)it * BATCH + b) * INFO_LEN;
            float* ob2 = out + ((size_t)ITERS * BATCH + b) * INFO_LEN;
            const bool last = (it == ITERS - 1);
            if (rkv.x >= 0) { ob[rkv.x] = v0; if (last) ob2[rkv.x] = v0; }
            if (rkv.y >= 0) { ob[rkv.y] = v1; if (last) ob2[rkv.y] = v1; }
            if (rkv.z >= 0) { ob[rkv.z] = v2; if (last) ob2[rkv.z] = v2; }
            if (rkv.w >= 0) { ob[rkv.w] = v3; if (last) ob2[rkv.w] = v3; }
        }
    }
}

extern "C" void kernel_launch(void* const* d_in, const int* in_sizes, int n_in,
                              void* d_out, int out_size, void* d_ws, size_t ws_size,
                              hipStream_t stream) {
    const float* rx   = (const float*)d_in[0];
    const int*   info = (const int*)d_in[1];
    float*       outp = (float*)d_out;
    polar_bp_r6<<<dim3(BATCH), dim3(256), 0, stream>>>(rx, info, outp);
}

// Round 7
// 39.149 us; speedup vs baseline: 4.2503x; 1.7968x over previous
//
#include <hip/hip_runtime.h>

constexpr int CODE_LEN = 1024;
constexpr int INFO_LEN = 512;
constexpr int BATCH    = 2048;
constexpr int ITERS    = 5;
#define CLIPV 15.0f

// f(a,b): v_xor + v_min(|a|,|b|) + v_and_or = 3 VALU
__device__ __forceinline__ float fop(float a, float b) {
    float m = fminf(fabsf(a), fabsf(b));
    unsigned s = (__float_as_uint(a) ^ __float_as_uint(b)) & 0x80000000u;
    return __uint_as_float(__float_as_uint(m) | s);
}
// clip = single v_med3_f32
__device__ __forceinline__ float clipf(float x) {
    return __builtin_amdgcn_fmed3f(x, -CLIPV, CLIPV);
}

// ---------------------------------------------------------------------------
// Layout scheme: position p (10 bits) lives at (wave, lane, slot) per group:
//  L0: slot=p10 lane54=p32 lane32=p54 lane10=p76 wave=p98   (stages 0,1; FR/RK)
//  L1: slot=p32 lane54=p10 lane32=p54 lane10=p76 wave=p98   (stages 2,3)
//  L2: slot=p54 lane54=p10 lane32=p32 lane10=p76 wave=p98   (stages 4,5)
//  L3: slot=p76 lane54=p10 lane32=p32 lane10=p54 wave=p98   (stages 6,7)
//  L4: slot=p98 lane54=p10 lane32=p32 lane10=p54 wave=p76   (stages 8,9; rx)
// Every stage is then a butterfly between REGISTER SLOTS (select-free).
// Group transitions convert only the boundary array: a slot <-> lane-bit-pair
// swap via per-wave LDS (no barrier; in-order DS), or slot <-> wave via the
// block buffer (1 barrier). S[s] holds left[s+1] before the right pass,
// right[s+1] after it; the left pass rewrites S[s-1] = left[s]. S[9]=rx.
// ---------------------------------------------------------------------------

// right-pass step, butterfly on slot bit0: pairs (0,1),(2,3). B = l -> out
#define RSTEP0(A, B) do { \
    float bu0=(B)[0], bl0=(B)[1], bu1=(B)[2], bl1=(B)[3]; \
    (B)[0]=clipf(fop((A)[0], bl0+(A)[1])); \
    (B)[1]=clipf(fop((A)[0], bu0)+(A)[1]); \
    (B)[2]=clipf(fop((A)[2], bl1+(A)[3])); \
    (B)[3]=clipf(fop((A)[2], bu1)+(A)[3]); } while(0)
// right-pass step, slot bit1: pairs (0,2),(1,3)
#define RSTEP1(A, B) do { \
    float bu0=(B)[0], bl0=(B)[2], bu1=(B)[1], bl1=(B)[3]; \
    (B)[0]=clipf(fop((A)[0], bl0+(A)[2])); \
    (B)[2]=clipf(fop((A)[0], bu0)+(A)[2]); \
    (B)[1]=clipf(fop((A)[1], bl1+(A)[3])); \
    (B)[3]=clipf(fop((A)[1], bu1)+(A)[3]); } while(0)
// left-pass step, slot bit0: A = r -> out (A := left[s])
#define LSTEP0(A, B) do { \
    float au0=(A)[0], al0=(A)[1], au1=(A)[2], al1=(A)[3]; \
    (A)[0]=clipf(fop((B)[0], (B)[1]+al0)); \
    (A)[1]=clipf(fop(au0, (B)[0])+(B)[1]); \
    (A)[2]=clipf(fop((B)[2], (B)[3]+al1)); \
    (A)[3]=clipf(fop(au1, (B)[2])+(B)[3]); } while(0)
// left-pass step, slot bit1
#define LSTEP1(A, B) do { \
    float au0=(A)[0], al0=(A)[2], au1=(A)[1], al1=(A)[3]; \
    (A)[0]=clipf(fop((B)[0], (B)[2]+al0)); \
    (A)[2]=clipf(fop(au0, (B)[0])+(B)[2]); \
    (A)[1]=clipf(fop((B)[1], (B)[3]+al1)); \
    (A)[3]=clipf(fop(au1, (B)[1])+(B)[3]); } while(0)

// in-wave conversion: swap slot <-> lane bits [BETA+1:BETA] of array arr[4].
// write own 4 slots contiguous (b128), read 4 scattered (imm offsets).
// Self-inverse; no barrier (same-wave DS is in-order).
#define CONV_W(arr, BETA) do { \
    float* wb_ = &WB[(t >> 6) * 256]; \
    const int l6_ = t & 63; \
    *(float4*)&wb_[l6_ * 4] = make_float4((arr)[0], (arr)[1], (arr)[2], (arr)[3]); \
    const int rb_ = ((l6_ & ~(3 << (BETA))) << 2) | ((l6_ >> (BETA)) & 3); \
    (arr)[0] = wb_[rb_]; \
    (arr)[1] = wb_[rb_ + (4  << (BETA))]; \
    (arr)[2] = wb_[rb_ + (8  << (BETA))]; \
    (arr)[3] = wb_[rb_ + (12 << (BETA))]; } while(0)

// cross-wave conversion: swap slot <-> wave bits. One barrier; XB0/XB1
// alternation makes write-after-read safe across iterations.
#define CONV_X(arr, XBUF) do { \
    *(float4*)&(XBUF)[t * 4] = make_float4((arr)[0], (arr)[1], (arr)[2], (arr)[3]); \
    __syncthreads(); \
    const int rb_ = (t & 63) * 4 + (t >> 6); \
    (arr)[0] = (XBUF)[rb_]; \
    (arr)[1] = (XBUF)[rb_ + 256]; \
    (arr)[2] = (XBUF)[rb_ + 512]; \
    (arr)[3] = (XBUF)[rb_ + 768]; } while(0)

__global__ __launch_bounds__(256, 4) void polar_bp_r7(const float* __restrict__ rx,
                                                      const int* __restrict__ info,
                                                      float* __restrict__ out) {
    __shared__ int   RK[CODE_LEN];    // rank table, stored in L0 flat order
    __shared__ float WB[CODE_LEN];    // per-wave conversion scratch (4x256)
    __shared__ float XB0[CODE_LEN];   // cross-wave buffers (alternating)
    __shared__ float XB1[CODE_LEN];

    const int t = threadIdx.x;
    const int b = blockIdx.x;

    // RK[L0-flat] = output rank or -1. flat(p) = p10 + p76*4 + p54*16 + p32*64 + p98*256
    *(int4*)&RK[t * 4] = make_int4(-1, -1, -1, -1);
    __syncthreads();
#pragma unroll
    for (int k = 0; k < 2; ++k) {
        int kk = t + 256 * k;
        int p  = info[kk];
        int fl = (p & 3) | (((p >> 6) & 3) << 2) | (((p >> 4) & 3) << 4)
               | (((p >> 2) & 3) << 6) | (((p >> 8) & 3) << 8);
        RK[fl] = kk;
    }
    __syncthreads();

    float S[10][4];
    // rx -> S[9] in L4 order: p = e*256 + t76*64 + t10*16 + t32*4 + t54
    {
        const float* rxb = rx + (size_t)b * CODE_LEN
                         + ((t >> 6) & 3) * 64 + (t & 3) * 16
                         + ((t >> 2) & 3) * 4 + ((t >> 4) & 3);
        S[9][0] = rxb[0];   S[9][1] = rxb[256];
        S[9][2] = rxb[512]; S[9][3] = rxb[768];
    }
#pragma unroll
    for (int s = 0; s < 9; ++s)
#pragma unroll
        for (int j = 0; j < 4; ++j) S[s][j] = 0.f;

#pragma unroll 1
    for (int it = 0; it < ITERS; ++it) {
        // ===================== RIGHT pass (s = 0..8) =====================
        {   // s0: r = frozen (rematerialized from RK), l = S[0]
            int4 rkv = *(const int4*)&RK[t * 4];
            float fr[4];
            fr[0] = rkv.x < 0 ? CLIPV : 0.f;  fr[1] = rkv.y < 0 ? CLIPV : 0.f;
            fr[2] = rkv.z < 0 ? CLIPV : 0.f;  fr[3] = rkv.w < 0 ? CLIPV : 0.f;
            RSTEP0(fr, S[0]);
        }
        RSTEP1(S[0], S[1]);        // s1
        CONV_W(S[1], 4);           // C01: S[1]=right[2]  L0->L1
        RSTEP0(S[1], S[2]);        // s2
        RSTEP1(S[2], S[3]);        // s3
        CONV_W(S[3], 2);           // C12: S[3]=right[4]  L1->L2
        RSTEP0(S[3], S[4]);        // s4
        RSTEP1(S[4], S[5]);        // s5
        CONV_W(S[5], 0);           // C23: S[5]=right[6]  L2->L3
        RSTEP0(S[5], S[6]);        // s6
        RSTEP1(S[6], S[7]);        // s7
        CONV_X(S[7], XB0);         // C34: S[7]=right[8]  L3->L4 (1 barrier)
        RSTEP0(S[7], S[8]);        // s8   (right[9]; right stage 9 unused)
        // ===================== LEFT pass (s = 9..0) ======================
        LSTEP1(S[8], S[9]);        // s9: l=rx,  writes S[8]=left[9]
        LSTEP0(S[7], S[8]);        // s8:        writes S[7]=left[8]
        CONV_X(S[7], XB1);         // C43: S[7]=left[8]   L4->L3 (1 barrier)
        LSTEP1(S[6], S[7]);        // s7
        LSTEP0(S[5], S[6]);        // s6
        CONV_W(S[5], 0);           // C32: S[5]=left[6]   L3->L2
        LSTEP1(S[4], S[5]);        // s5
        LSTEP0(S[3], S[4]);        // s4
        CONV_W(S[3], 2);           // C21: S[3]=left[4]   L2->L1
        LSTEP1(S[2], S[3]);        // s3
        LSTEP0(S[1], S[2]);        // s2
        CONV_W(S[1], 4);           // C10: S[1]=left[2]   L1->L0
        LSTEP1(S[0], S[1]);        // s1:        writes S[0]=left[1]
        {   // s0: emit left[0] at info positions (right[0]=0 there), L0 order
            int4 rkv = *(const int4*)&RK[t * 4];
            float f0 = rkv.x < 0 ? CLIPV : 0.f, f1 = rkv.y < 0 ? CLIPV : 0.f;
            float f2 = rkv.z < 0 ? CLIPV : 0.f, f3 = rkv.w < 0 ? CLIPV : 0.f;
            float v0 = clipf(fop(S[0][0], S[0][1] + f1));
            float v1 = clipf(fop(f0, S[0][0]) + S[0][1]);
            float v2 = clipf(fop(S[0][2], S[0][3] + f3));
            float v3 = clipf(fop(f2, S[0][2]) + S[0][3]);
            float* ob = out + ((size_t)it * BATCH + b) * INFO_LEN;
            if (rkv.x >= 0) ob[rkv.x] = v0;
            if (rkv.y >= 0) ob[rkv.y] = v1;
            if (rkv.z >= 0) ob[rkv.z] = v2;
            if (rkv.w >= 0) ob[rkv.w] = v3;
            if (it == ITERS - 1) {
                float* ob2 = ob + (size_t)BATCH * INFO_LEN;
                if (rkv.x >= 0) ob2[rkv.x] = v0;
                if (rkv.y >= 0) ob2[rkv.y] = v1;
                if (rkv.z >= 0) ob2[rkv.z] = v2;
                if (rkv.w >= 0) ob2[rkv.w] = v3;
            }
        }
    }
}

extern "C" void kernel_launch(void* const* d_in, const int* in_sizes, int n_in,
                              void* d_out, int out_size, void* d_ws, size_t ws_size,
                              hipStream_t stream) {
    const float* rx   = (const float*)d_in[0];
    const int*   info = (const int*)d_in[1];
    float*       outp = (float*)d_out;
    polar_bp_r7<<<dim3(BATCH), dim3(256), 0, stream>>>(rx, info, outp);
}

// Round 8
// 38.404 us; speedup vs baseline: 4.3328x; 1.0194x over previous
//
#include <hip/hip_runtime.h>

constexpr int CODE_LEN = 1024;
constexpr int INFO_LEN = 512;
constexpr int BATCH    = 2048;
constexpr int ITERS    = 5;
#define CLIPV 15.0f

// f(a,b): v_xor + v_min(|a|,|b| modifiers) + v_and_or = 3 VALU
__device__ __forceinline__ float fop(float a, float b) {
    float m = fminf(fabsf(a), fabsf(b));
    unsigned s = (__float_as_uint(a) ^ __float_as_uint(b)) & 0x80000000u;
    return __uint_as_float(__float_as_uint(m) | s);
}
// clip = single v_med3_f32
__device__ __forceinline__ float clipf(float x) {
    return __builtin_amdgcn_fmed3f(x, -CLIPV, CLIPV);
}

// ---------------------------------------------------------------------------
// R7 layout scheme (validated): position p lives at (wave,lane,slot) per
// group; every butterfly is between REGISTER SLOTS (select-free). Group
// transitions convert one boundary array via LDS.
// R8 changes:
//  * CONV_W uses sigma(g)=g^(g>>2) group swizzle -> all reads/writes land
//    2-per-bank (free) instead of 4/8-way conflicts at BETA=2/0.
//  * All LDS offsets are iteration-invariant -> precomputed into registers.
//  * Redundant clips removed: clip(fop(a,..)) with a already in [-15,15]
//    is identity (|fop|<=|a|). Applies to all u-outputs EXCEPT left stage 9
//    (min-arg is unclipped rx). l-outputs (f+x, |sum|<=30) keep clip.
//  * rk/fr hoisted to registers; duplicate final row stored after the loop.
// ---------------------------------------------------------------------------

// right-pass step, slot bit0: pairs (0,1),(2,3). A=r(clipped), B=l -> out
#define RSTEP0(A, B) do { \
    float bu0=(B)[0], bl0=(B)[1], bu1=(B)[2], bl1=(B)[3]; \
    (B)[0]=fop((A)[0], bl0+(A)[1]); \
    (B)[1]=clipf(fop((A)[0], bu0)+(A)[1]); \
    (B)[2]=fop((A)[2], bl1+(A)[3]); \
    (B)[3]=clipf(fop((A)[2], bu1)+(A)[3]); } while(0)
// right-pass step, slot bit1: pairs (0,2),(1,3)
#define RSTEP1(A, B) do { \
    float bu0=(B)[0], bl0=(B)[2], bu1=(B)[1], bl1=(B)[3]; \
    (B)[0]=fop((A)[0], bl0+(A)[2]); \
    (B)[2]=clipf(fop((A)[0], bu0)+(A)[2]); \
    (B)[1]=fop((A)[1], bl1+(A)[3]); \
    (B)[3]=clipf(fop((A)[1], bu1)+(A)[3]); } while(0)
// left-pass step, slot bit0: A=r, B=l (clipped, s<=8) -> writes A=left[s]
#define LSTEP0(A, B) do { \
    float au0=(A)[0], al0=(A)[1], au1=(A)[2], al1=(A)[3]; \
    (A)[0]=fop((B)[0], (B)[1]+al0); \
    (A)[1]=clipf(fop(au0, (B)[0])+(B)[1]); \
    (A)[2]=fop((B)[2], (B)[3]+al1); \
    (A)[3]=clipf(fop(au1, (B)[2])+(B)[3]); } while(0)
// left-pass step, slot bit1 (B clipped, s<=8)
#define LSTEP1(A, B) do { \
    float au0=(A)[0], al0=(A)[2], au1=(A)[1], al1=(A)[3]; \
    (A)[0]=fop((B)[0], (B)[2]+al0); \
    (A)[2]=clipf(fop(au0, (B)[0])+(B)[2]); \
    (A)[1]=fop((B)[1], (B)[3]+al1); \
    (A)[3]=clipf(fop(au1, (B)[1])+(B)[3]); } while(0)
// left-pass step, slot bit1, stage 9: B = rx (UNclipped) -> keep u-clip
#define LSTEP1C(A, B) do { \
    float au0=(A)[0], al0=(A)[2], au1=(A)[1], al1=(A)[3]; \
    (A)[0]=clipf(fop((B)[0], (B)[2]+al0)); \
    (A)[2]=clipf(fop(au0, (B)[0])+(B)[2]); \
    (A)[1]=clipf(fop((B)[1], (B)[3]+al1)); \
    (A)[3]=clipf(fop(au1, (B)[1])+(B)[3]); } while(0)

// in-wave conversion: swap slot <-> lane-bit-pair; sigma-swizzled, offsets
// precomputed. Same-wave DS is in-order -> no barrier.
#define CONV_W(arr, R) do { \
    *(float4*)&WB[offW] = make_float4((arr)[0], (arr)[1], (arr)[2], (arr)[3]); \
    float c0_ = WB[(R)[0]], c1_ = WB[(R)[1]], c2_ = WB[(R)[2]], c3_ = WB[(R)[3]]; \
    (arr)[0]=c0_; (arr)[1]=c1_; (arr)[2]=c2_; (arr)[3]=c3_; } while(0)

// cross-wave conversion: swap slot <-> wave bits. One barrier; XB0/XB1
// alternation keeps write-after-read barrier-separated across uses.
#define CONV_X(arr, XBUF) do { \
    *(float4*)&(XBUF)[offXw] = make_float4((arr)[0], (arr)[1], (arr)[2], (arr)[3]); \
    __syncthreads(); \
    (arr)[0]=(XBUF)[offXr];     (arr)[1]=(XBUF)[offXr+256]; \
    (arr)[2]=(XBUF)[offXr+512]; (arr)[3]=(XBUF)[offXr+768]; } while(0)

__global__ __launch_bounds__(256, 4) void polar_bp_r8(const float* __restrict__ rx,
                                                      const int* __restrict__ info,
                                                      float* __restrict__ out) {
    __shared__ int   RK[CODE_LEN];    // rank table in L0 flat order (init only)
    __shared__ float WB[CODE_LEN];    // per-wave conversion scratch (4x256)
    __shared__ float XB0[CODE_LEN];   // cross-wave buffers (alternating)
    __shared__ float XB1[CODE_LEN];

    const int t = threadIdx.x;
    const int b = blockIdx.x;

    // RK[L0-flat] = rank or -1. flat(p) = p10 | p76<<2 | p54<<4 | p32<<6 | p98<<8
    *(int4*)&RK[t * 4] = make_int4(-1, -1, -1, -1);
    __syncthreads();
#pragma unroll
    for (int k = 0; k < 2; ++k) {
        int kk = t + 256 * k;
        int p  = info[kk];
        int fl = (p & 3) | (((p >> 6) & 3) << 2) | (((p >> 4) & 3) << 4)
               | (((p >> 2) & 3) << 6) | (((p >> 8) & 3) << 8);
        RK[fl] = kk;
    }
    __syncthreads();

    // ---- precomputed LDS word offsets (iteration-invariant) ----
    const int l6 = t & 63;
    const int wbase = (t >> 6) * 256;
    const int offW  = wbase + 4 * (l6 ^ (l6 >> 2));   // sigma-swizzled write
    int offR4[4], offR2[4], offR0[4];
#pragma unroll
    for (int k = 0; k < 4; ++k) {
        int g4 = (l6 & ~(3 << 4)) | (k << 4);
        int g2 = (l6 & ~(3 << 2)) | (k << 2);
        int g0 = (l6 & ~3) | k;
        offR4[k] = wbase + 4 * (g4 ^ (g4 >> 2)) + ((l6 >> 4) & 3);
        offR2[k] = wbase + 4 * (g2 ^ (g2 >> 2)) + ((l6 >> 2) & 3);
        offR0[k] = wbase + 4 * (g0 ^ (g0 >> 2)) + (l6 & 3);
    }
    const int offXw = t * 4;
    const int offXr = (t & 63) * 4 + (t >> 6);

    // ---- per-thread constants: ranks + frozen vector (registers) ----
    const int4 rkv = *(const int4*)&RK[t * 4];
    float fr[4];
    fr[0] = rkv.x < 0 ? CLIPV : 0.f;  fr[1] = rkv.y < 0 ? CLIPV : 0.f;
    fr[2] = rkv.z < 0 ? CLIPV : 0.f;  fr[3] = rkv.w < 0 ? CLIPV : 0.f;

    float S[10][4];
    // rx -> S[9] in L4 order: p = e*256 + t76*64 + t10*16 + t32*4 + t54
    {
        const float* rxb = rx + (size_t)b * CODE_LEN
                         + ((t >> 6) & 3) * 64 + (t & 3) * 16
                         + ((t >> 2) & 3) * 4 + ((t >> 4) & 3);
        S[9][0] = rxb[0];   S[9][1] = rxb[256];
        S[9][2] = rxb[512]; S[9][3] = rxb[768];
    }
#pragma unroll
    for (int s = 0; s < 9; ++s)
#pragma unroll
        for (int j = 0; j < 4; ++j) S[s][j] = 0.f;

    float v0, v1, v2, v3;
    float* ob = out + (size_t)b * INFO_LEN;
    const size_t obstride = (size_t)BATCH * INFO_LEN;

#pragma unroll 1
    for (int it = 0; it < ITERS; ++it) {
        // ===================== RIGHT pass (s = 0..8) =====================
        RSTEP0(fr, S[0]);          // s0 (r = frozen)
        RSTEP1(S[0], S[1]);        // s1
        CONV_W(S[1], offR4);       // C01: S[1]=right[2]  L0->L1
        RSTEP0(S[1], S[2]);        // s2
        RSTEP1(S[2], S[3]);        // s3
        CONV_W(S[3], offR2);       // C12: S[3]=right[4]  L1->L2
        RSTEP0(S[3], S[4]);        // s4
        RSTEP1(S[4], S[5]);        // s5
        CONV_W(S[5], offR0);       // C23: S[5]=right[6]  L2->L3
        RSTEP0(S[5], S[6]);        // s6
        RSTEP1(S[6], S[7]);        // s7
        CONV_X(S[7], XB0);         // C34: S[7]=right[8]  L3->L4 (barrier)
        RSTEP0(S[7], S[8]);        // s8 (right[9]; right s9 unused)
        // ===================== LEFT pass (s = 9..0) ======================
        LSTEP1C(S[8], S[9]);       // s9: l = rx (unclipped) -> keep u-clip
        LSTEP0(S[7], S[8]);        // s8
        CONV_X(S[7], XB1);         // C43: S[7]=left[8]   L4->L3 (barrier)
        LSTEP1(S[6], S[7]);        // s7
        LSTEP0(S[5], S[6]);        // s6
        CONV_W(S[5], offR0);       // C32: S[5]=left[6]   L3->L2
        LSTEP1(S[4], S[5]);        // s5
        LSTEP0(S[3], S[4]);        // s4
        CONV_W(S[3], offR2);       // C21: S[3]=left[4]   L2->L1
        LSTEP1(S[2], S[3]);        // s3
        LSTEP0(S[1], S[2]);        // s2
        CONV_W(S[1], offR4);       // C10: S[1]=left[2]   L1->L0
        LSTEP1(S[0], S[1]);        // s1 -> S[0]=left[1]
        // s0: emit left[0] at info positions (right[0]=0 there), L0 order.
        // v0/v2 are u-outputs with clipped min-arg -> no clip needed.
        v0 = fop(S[0][0], S[0][1] + fr[1]);
        v1 = clipf(fop(fr[0], S[0][0]) + S[0][1]);
        v2 = fop(S[0][2], S[0][3] + fr[3]);
        v3 = clipf(fop(fr[2], S[0][2]) + S[0][3]);
        if (rkv.x >= 0) ob[rkv.x] = v0;
        if (rkv.y >= 0) ob[rkv.y] = v1;
        if (rkv.z >= 0) ob[rkv.z] = v2;
        if (rkv.w >= 0) ob[rkv.w] = v3;
        ob += obstride;
    }
    // duplicate row: out[ITERS] = out[ITERS-1] (ob now points at row ITERS)
    if (rkv.x >= 0) ob[rkv.x] = v0;
    if (rkv.y >= 0) ob[rkv.y] = v1;
    if (rkv.z >= 0) ob[rkv.z] = v2;
    if (rkv.w >= 0) ob[rkv.w] = v3;
}

extern "C" void kernel_launch(void* const* d_in, const int* in_sizes, int n_in,
                              void* d_out, int out_size, void* d_ws, size_t ws_size,
                              hipStream_t stream) {
    const float* rx   = (const float*)d_in[0];
    const int*   info = (const int*)d_in[1];
    float*       outp = (float*)d_out;
    polar_bp_r8<<<dim3(BATCH), dim3(256), 0, stream>>>(rx, info, outp);
}

// Round 9
// 32.320 us; speedup vs baseline: 5.1485x; 1.1883x over previous
//
#include <hip/hip_runtime.h>

constexpr int CODE_LEN = 1024;
constexpr int INFO_LEN = 512;
constexpr int BATCH    = 2048;
constexpr int ITERS    = 5;
#define CLIPV 15.0f

// f(a,b) = sign(a)*sign(b)*min(|a|,|b|) -- forced 3-inst codegen:
// v_xor_b32 + v_min_f32(|a|,|b|) + v_and_or_b32 (sign mask in SGPR).
__device__ __forceinline__ float fop(float a, float b) {
    unsigned x; float m, r;
    asm("v_xor_b32 %0, %1, %2" : "=v"(x) : "v"(a), "v"(b));
    asm("v_min_f32 %0, |%1|, |%2|" : "=v"(m) : "v"(a), "v"(b));
    asm("v_and_or_b32 %0, %1, %2, %3" : "=v"(r) : "v"(x), "s"(0x80000000u), "v"(m));
    return r;
}
// clip = single v_med3_f32
__device__ __forceinline__ float clipf(float x) {
    return __builtin_amdgcn_fmed3f(x, -CLIPV, CLIPV);
}

// ---------------------------------------------------------------------------
// R7/R8 layout scheme (validated): position p lives at (wave,lane,slot) per
// group; every butterfly is between REGISTER SLOTS (select-free); group
// transitions convert one boundary array via sigma-swizzled LDS (CONV_W, no
// barrier) or the block-wide buffer (CONV_X, 1 barrier). Redundant clips
// removed (u-outputs with already-clipped min-arg). R9 adds: asm-tight fop
// and a peeled iteration-0 right pass (left arrays are all zero there:
// u' = fop(r_u, r_l), l' = r_l; all values >= +0, no -0 hazard).
// ---------------------------------------------------------------------------

#define RSTEP0(A, B) do { \
    float bu0=(B)[0], bl0=(B)[1], bu1=(B)[2], bl1=(B)[3]; \
    (B)[0]=fop((A)[0], bl0+(A)[1]); \
    (B)[1]=clipf(fop((A)[0], bu0)+(A)[1]); \
    (B)[2]=fop((A)[2], bl1+(A)[3]); \
    (B)[3]=clipf(fop((A)[2], bu1)+(A)[3]); } while(0)
#define RSTEP1(A, B) do { \
    float bu0=(B)[0], bl0=(B)[2], bu1=(B)[1], bl1=(B)[3]; \
    (B)[0]=fop((A)[0], bl0+(A)[2]); \
    (B)[2]=clipf(fop((A)[0], bu0)+(A)[2]); \
    (B)[1]=fop((A)[1], bl1+(A)[3]); \
    (B)[3]=clipf(fop((A)[1], bu1)+(A)[3]); } while(0)
#define LSTEP0(A, B) do { \
    float au0=(A)[0], al0=(A)[1], au1=(A)[2], al1=(A)[3]; \
    (A)[0]=fop((B)[0], (B)[1]+al0); \
    (A)[1]=clipf(fop(au0, (B)[0])+(B)[1]); \
    (A)[2]=fop((B)[2], (B)[3]+al1); \
    (A)[3]=clipf(fop(au1, (B)[2])+(B)[3]); } while(0)
#define LSTEP1(A, B) do { \
    float au0=(A)[0], al0=(A)[2], au1=(A)[1], al1=(A)[3]; \
    (A)[0]=fop((B)[0], (B)[2]+al0); \
    (A)[2]=clipf(fop(au0, (B)[0])+(B)[2]); \
    (A)[1]=fop((B)[1], (B)[3]+al1); \
    (A)[3]=clipf(fop(au1, (B)[1])+(B)[3]); } while(0)
// stage-9 left step: B = rx (UNclipped) -> keep u-clip
#define LSTEP1C(A, B) do { \
    float au0=(A)[0], al0=(A)[2], au1=(A)[1], al1=(A)[3]; \
    (A)[0]=clipf(fop((B)[0], (B)[2]+al0)); \
    (A)[2]=clipf(fop(au0, (B)[0])+(B)[2]); \
    (A)[1]=clipf(fop((B)[1], (B)[3]+al1)); \
    (A)[3]=clipf(fop(au1, (B)[1])+(B)[3]); } while(0)
// iteration-0 right steps (l == 0): u' = fop(r_u, r_l), l' = r_l
#define RSTEP0Z(A, B) do { \
    (B)[0]=fop((A)[0], (A)[1]); (B)[1]=(A)[1]; \
    (B)[2]=fop((A)[2], (A)[3]); (B)[3]=(A)[3]; } while(0)
#define RSTEP1Z(A, B) do { \
    (B)[0]=fop((A)[0], (A)[2]); (B)[2]=(A)[2]; \
    (B)[1]=fop((A)[1], (A)[3]); (B)[3]=(A)[3]; } while(0)

#define CONV_W(arr, R) do { \
    *(float4*)&WB[offW] = make_float4((arr)[0], (arr)[1], (arr)[2], (arr)[3]); \
    float c0_ = WB[(R)[0]], c1_ = WB[(R)[1]], c2_ = WB[(R)[2]], c3_ = WB[(R)[3]]; \
    (arr)[0]=c0_; (arr)[1]=c1_; (arr)[2]=c2_; (arr)[3]=c3_; } while(0)

#define CONV_X(arr, XBUF) do { \
    *(float4*)&(XBUF)[offXw] = make_float4((arr)[0], (arr)[1], (arr)[2], (arr)[3]); \
    __syncthreads(); \
    (arr)[0]=(XBUF)[offXr];     (arr)[1]=(XBUF)[offXr+256]; \
    (arr)[2]=(XBUF)[offXr+512]; (arr)[3]=(XBUF)[offXr+768]; } while(0)

#define RIGHT_PASS(S0Z) do { \
    RSTEP1(S[0], S[1]); \
    CONV_W(S[1], offR4); \
    RSTEP0(S[1], S[2]); \
    RSTEP1(S[2], S[3]); \
    CONV_W(S[3], offR2); \
    RSTEP0(S[3], S[4]); \
    RSTEP1(S[4], S[5]); \
    CONV_W(S[5], offR0); \
    RSTEP0(S[5], S[6]); \
    RSTEP1(S[6], S[7]); \
    CONV_X(S[7], XB0); \
    RSTEP0(S[7], S[8]); } while(0)

__global__ __launch_bounds__(256, 4) void polar_bp_r9(const float* __restrict__ rx,
                                                      const int* __restrict__ info,
                                                      float* __restrict__ out) {
    __shared__ int   RK[CODE_LEN];    // rank table in L0 flat order (init only)
    __shared__ float WB[CODE_LEN];    // per-wave conversion scratch (4x256)
    __shared__ float XB0[CODE_LEN];   // cross-wave buffers
    __shared__ float XB1[CODE_LEN];

    const int t = threadIdx.x;
    const int b = blockIdx.x;

    // RK[L0-flat] = rank or -1. flat(p) = p10 | p76<<2 | p54<<4 | p32<<6 | p98<<8
    *(int4*)&RK[t * 4] = make_int4(-1, -1, -1, -1);
    __syncthreads();
#pragma unroll
    for (int k = 0; k < 2; ++k) {
        int kk = t + 256 * k;
        int p  = info[kk];
        int fl = (p & 3) | (((p >> 6) & 3) << 2) | (((p >> 4) & 3) << 4)
               | (((p >> 2) & 3) << 6) | (((p >> 8) & 3) << 8);
        RK[fl] = kk;
    }
    __syncthreads();

    // ---- precomputed LDS word offsets (iteration-invariant) ----
    const int l6 = t & 63;
    const int wbase = (t >> 6) * 256;
    const int offW  = wbase + 4 * (l6 ^ (l6 >> 2));   // sigma-swizzled write
    int offR4[4], offR2[4], offR0[4];
#pragma unroll
    for (int k = 0; k < 4; ++k) {
        int g4 = (l6 & ~(3 << 4)) | (k << 4);
        int g2 = (l6 & ~(3 << 2)) | (k << 2);
        int g0 = (l6 & ~3) | k;
        offR4[k] = wbase + 4 * (g4 ^ (g4 >> 2)) + ((l6 >> 4) & 3);
        offR2[k] = wbase + 4 * (g2 ^ (g2 >> 2)) + ((l6 >> 2) & 3);
        offR0[k] = wbase + 4 * (g0 ^ (g0 >> 2)) + (l6 & 3);
    }
    const int offXw = t * 4;
    const int offXr = (t & 63) * 4 + (t >> 6);

    // ---- per-thread constants: ranks + frozen vector (registers) ----
    const int4 rkv = *(const int4*)&RK[t * 4];
    float fr[4];
    fr[0] = rkv.x < 0 ? CLIPV : 0.f;  fr[1] = rkv.y < 0 ? CLIPV : 0.f;
    fr[2] = rkv.z < 0 ? CLIPV : 0.f;  fr[3] = rkv.w < 0 ? CLIPV : 0.f;

    float S[10][4];
    // rx -> S[9] in L4 order: p = e*256 + t76*64 + t10*16 + t32*4 + t54
    {
        const float* rxb = rx + (size_t)b * CODE_LEN
                         + ((t >> 6) & 3) * 64 + (t & 3) * 16
                         + ((t >> 2) & 3) * 4 + ((t >> 4) & 3);
        S[9][0] = rxb[0];   S[9][1] = rxb[256];
        S[9][2] = rxb[512]; S[9][3] = rxb[768];
    }

    // ===== iteration-0 RIGHT pass, peeled: all left arrays are zero =====
    RSTEP0Z(fr, S[0]);         // s0
    RSTEP1Z(S[0], S[1]);       // s1
    CONV_W(S[1], offR4);       // C01  L0->L1
    RSTEP0Z(S[1], S[2]);       // s2
    RSTEP1Z(S[2], S[3]);       // s3
    CONV_W(S[3], offR2);       // C12  L1->L2
    RSTEP0Z(S[3], S[4]);       // s4
    RSTEP1Z(S[4], S[5]);       // s5
    CONV_W(S[5], offR0);       // C23  L2->L3
    RSTEP0Z(S[5], S[6]);       // s6
    RSTEP1Z(S[6], S[7]);       // s7
    CONV_X(S[7], XB0);         // C34  L3->L4 (barrier)
    RSTEP0Z(S[7], S[8]);       // s8  (right stage 9 output unused)

    float v0, v1, v2, v3;
    float* ob = out + (size_t)b * INFO_LEN;
    const size_t obstride = (size_t)BATCH * INFO_LEN;

#pragma unroll 1
    for (int it = 0; it < ITERS; ++it) {
        // ===================== LEFT pass (s = 9..0) ======================
        LSTEP1C(S[8], S[9]);       // s9: l = rx (unclipped) -> keep u-clip
        LSTEP0(S[7], S[8]);        // s8
        CONV_X(S[7], XB1);         // C43  L4->L3 (barrier)
        LSTEP1(S[6], S[7]);        // s7
        LSTEP0(S[5], S[6]);        // s6
        CONV_W(S[5], offR0);       // C32  L3->L2
        LSTEP1(S[4], S[5]);        // s5
        LSTEP0(S[3], S[4]);        // s4
        CONV_W(S[3], offR2);       // C21  L2->L1
        LSTEP1(S[2], S[3]);        // s3
        LSTEP0(S[1], S[2]);        // s2
        CONV_W(S[1], offR4);       // C10  L1->L0
        LSTEP1(S[0], S[1]);        // s1 -> S[0] = left[1]
        // s0: emit left[0] at info positions (right[0] = 0 there), L0 order
        v0 = fop(S[0][0], S[0][1] + fr[1]);
        v1 = clipf(fop(fr[0], S[0][0]) + S[0][1]);
        v2 = fop(S[0][2], S[0][3] + fr[3]);
        v3 = clipf(fop(fr[2], S[0][2]) + S[0][3]);
        if (rkv.x >= 0) ob[rkv.x] = v0;
        if (rkv.y >= 0) ob[rkv.y] = v1;
        if (rkv.z >= 0) ob[rkv.z] = v2;
        if (rkv.w >= 0) ob[rkv.w] = v3;
        ob += obstride;
        // ===================== RIGHT pass (s = 0..8) =====================
        if (it != ITERS - 1) {
            RSTEP0(fr, S[0]);          // s0 (r = frozen)
            RSTEP1(S[0], S[1]);        // s1
            CONV_W(S[1], offR4);       // C01
            RSTEP0(S[1], S[2]);        // s2
            RSTEP1(S[2], S[3]);        // s3
            CONV_W(S[3], offR2);       // C12
            RSTEP0(S[3], S[4]);        // s4
            RSTEP1(S[4], S[5]);        // s5
            CONV_W(S[5], offR0);       // C23
            RSTEP0(S[5], S[6]);        // s6
            RSTEP1(S[6], S[7]);        // s7
            CONV_X(S[7], XB0);         // C34 (barrier)
            RSTEP0(S[7], S[8]);        // s8
        }
    }
    // duplicate row: out[ITERS] = out[ITERS-1] (ob now points at row ITERS)
    if (rkv.x >= 0) ob[rkv.x] = v0;
    if (rkv.y >= 0) ob[rkv.y] = v1;
    if (rkv.z >= 0) ob[rkv.z] = v2;
    if (rkv.w >= 0) ob[rkv.w] = v3;
}

extern "C" void kernel_launch(void* const* d_in, const int* in_sizes, int n_in,
                              void* d_out, int out_size, void* d_ws, size_t ws_size,
                              hipStream_t stream) {
    const float* rx   = (const float*)d_in[0];
    const int*   info = (const int*)d_in[1];
    float*       outp = (float*)d_out;
    polar_bp_r9<<<dim3(BATCH), dim3(256), 0, stream>>>(rx, info, outp);
}